// Round 4
// baseline (349.427 us; speedup 1.0000x reference)
//
#include <hip/hip_runtime.h>
#include <math.h>

#define BATCH 16
#define NN 25200
#define NCLS 80
#define K_PRE 1024
#define MAX_DET 300
#define CONF_T 0.4f
#define IOU_T 0.45f
#define TBIAS 0x3E000000u
// key layout (47 bits): t(25) << 22 | (NN-1-n)(15) << 7 | cls(7)
// (t, n) unique => cls in the low bits never affects sort order.
#define RROWS 128
#define STHREADS 512

// ---------------------------------------------------------------------------
// K1: LDS-staged score + first-max argmax -> 47-bit key per anchor.
// ---------------------------------------------------------------------------
__global__ void __launch_bounds__(STHREADS) score_kernel(
    const float* __restrict__ pred, unsigned long long* __restrict__ keys) {
    __shared__ float srow[RROWS * 85];

    const int tile = blockIdx.x, b = blockIdx.y, tid = threadIdx.x;
    const int row0 = tile * RROWS;
    int nrows = NN - row0;
    if (nrows > RROWS) nrows = RROWS;

    const float4* g4 = (const float4*)(pred + ((size_t)b * NN + row0) * 85);
    float4* l4 = (float4*)srow;
    const int nf4 = (nrows * 85) >> 2;  // nrows*85 % 4 == 0 always
    for (int i = tid; i < nf4; i += STHREADS) l4[i] = g4[i];
    __syncthreads();

    const int r = tid >> 2, sub = tid & 3;
    float best = 0.0f;
    int bc = sub * 20;
    float obj = 0.0f;
    if (r < nrows) {
        obj = srow[r * 85 + 4];
        if (obj > CONF_T) {
            const float* cp = &srow[r * 85 + 5 + sub * 20];
#pragma unroll
            for (int i = 0; i < 20; ++i) {
                float v = cp[i] * obj;
                if (v > best) { best = v; bc = sub * 20 + i; }  // first-max
            }
        }
    }
#pragma unroll
    for (int d = 1; d < 4; d <<= 1) {
        float ov = __shfl_xor(best, d);
        int oc = __shfl_xor(bc, d);
        if (ov > best || (ov == best && oc < bc)) { best = ov; bc = oc; }
    }
    if (r < nrows && sub == 0) {
        unsigned t = (obj > CONF_T && best > CONF_T)
                         ? (__float_as_uint(best) - TBIAS) : 0u;
        int n = row0 + r;
        keys[(size_t)b * NN + n] =
            ((unsigned long long)t << 22) |
            ((unsigned long long)(unsigned)(NN - 1 - n) << 7) | (unsigned)bc;
    }
}

// ---------------------------------------------------------------------------
// K2: one block per batch. hist -> exact digit select -> compact -> bitonic
// sort (2048) -> decode boxes -> wave-local per-class greedy NMS -> rank ->
// write 300x89 rows. Zeroes its own output slab (no memsets needed).
// ---------------------------------------------------------------------------
__global__ void __launch_bounds__(1024) fused_kernel(
    const unsigned long long* __restrict__ keys, const float* __restrict__ pred,
    const float* __restrict__ conf_logits, const float* __restrict__ logits,
    const float* __restrict__ head, float* __restrict__ out) {
    __shared__ unsigned sA[1024], sB[1024];
    __shared__ unsigned long long skeys[2048];
    __shared__ float bx0[K_PRE], by0[K_PRE], bx1[K_PRE], by1[K_PRE],
        bar[K_PRE];
    __shared__ short mlist[16 * 256];
    __shared__ unsigned char kf_s[K_PRE];
    __shared__ unsigned sel_d0, sel_cnt;
    volatile unsigned char* kf = kf_s;

    const int b = blockIdx.x, tid = threadIdx.x;
    const unsigned long long* bk = keys + (size_t)b * NN;

    // zero this batch's output slab (harness poisons d_out with 0xAA)
    float* ob = out + (size_t)b * MAX_DET * 89;
    for (int i = tid; i < MAX_DET * 89; i += 1024) ob[i] = 0.0f;

    sA[tid] = 0u;
    skeys[tid] = 0ull;
    skeys[tid + 1024] = 0ull;
    if (tid == 0) { sel_d0 = 0u; sel_cnt = 0u; }
    __syncthreads();

    // 10-bit digit histogram of valid keys
    for (int base = 0; base < 25600; base += 1024) {
        int i = base + tid;
        if (i < NN) {
            unsigned t = (unsigned)(bk[i] >> 22);
            if (t) atomicAdd(&sA[t >> 15], 1u);
        }
    }
    __syncthreads();

    // suffix-inclusive scan: src[d] = #keys with digit >= d
    unsigned* src = sA;
    unsigned* dst = sB;
    for (int off = 1; off < 1024; off <<= 1) {
        dst[tid] = src[tid] + ((tid + off < 1024) ? src[tid + off] : 0u);
        __syncthreads();
        unsigned* t2 = src; src = dst; dst = t2;
    }
    unsigned total = src[0];
    unsigned K = total < 1024u ? total : 1024u;
    if (total) {
        unsigned geq = src[tid];
        unsigned gt = (tid < 1023) ? src[tid + 1] : 0u;
        if (gt < K && K <= geq) sel_d0 = (unsigned)tid;  // unique writer
    }
    __syncthreads();
    const unsigned d0 = sel_d0;

    // compact keys with digit >= d0 (~K + one bucket ≈ 1070 << 2048)
    for (int base = 0; base < 25600; base += 1024) {
        int i = base + tid;
        if (i < NN) {
            unsigned long long key = bk[i];
            unsigned t = (unsigned)(key >> 22);
            if (t && (t >> 15) >= d0) {
                unsigned p = atomicAdd(&sel_cnt, 1u);
                if (p < 2048u) skeys[p] = key;
            }
        }
    }
    __syncthreads();

    // bitonic sort 2048 descending, thread owns pair (i, i|j)
    for (unsigned k2 = 2; k2 <= 2048; k2 <<= 1) {
        for (unsigned j = k2 >> 1; j > 0; j >>= 1) {
            unsigned i = (((unsigned)tid & ~(j - 1)) << 1) | ((unsigned)tid & (j - 1));
            unsigned ixj = i | j;
            unsigned long long a = skeys[i], c = skeys[ixj];
            bool desc = ((i & k2) == 0u);
            if (desc ? (a < c) : (a > c)) { skeys[i] = c; skeys[ixj] = a; }
            __syncthreads();
        }
    }

    // decode candidate tid: gather box from pred
    unsigned long long mykey = skeys[tid];
    unsigned t = (unsigned)(mykey >> 22);
    int n = NN - 1 - (int)((mykey >> 7) & 32767u);
    if (t) {
        const float* row = pred + ((size_t)b * NN + n) * 85;
        float x = row[0], y = row[1], w = row[2], h = row[3];
        float x0 = x - w * 0.5f, y0 = y - h * 0.5f;
        float x1 = x + w * 0.5f, y1 = y + h * 0.5f;
        bx0[tid] = x0; by0[tid] = y0; bx1[tid] = x1; by1[tid] = y1;
        bar[tid] = (x1 - x0) * (y1 - y0);
        kf_s[tid] = 1;
    } else {
        kf_s[tid] = 0;
    }
    __syncthreads();

    // wave-local per-class greedy NMS: wave w handles classes w, w+16, ...
    const int wave = tid >> 6, lane = tid & 63;
    short* ml = &mlist[wave * 256];
    for (int q = 0; q < 5; ++q) {
        int c = wave + 16 * q;
        int m = 0;
        for (int chunk = 0; chunk < 16; ++chunk) {
            int i = chunk * 64 + lane;
            unsigned long long kk = skeys[i];
            bool my = ((kk >> 22) != 0ull) && ((int)(kk & 127u) == c);
            unsigned long long bal = __ballot(my);
            if (my) {
                int pos = __popcll(bal & ((1ull << lane) - 1ull));
                if (m + pos < 256) ml[m + pos] = (short)i;
            }
            m += __popcll(bal);
        }
        if (m > 256) m = 256;
        for (int i = 0; i < m - 1; ++i) {
            __builtin_amdgcn_wave_barrier();
            int ci = ml[i];
            if (kf[ci]) {
                float ax0 = bx0[ci], ay0 = by0[ci];
                float ax1 = bx1[ci], ay1 = by1[ci];
                float aa = bar[ci];
                for (int j = i + 1 + lane; j < m; j += 64) {
                    int cj = ml[j];
                    if (kf[cj]) {
                        float lx = fmaxf(ax0, bx0[cj]);
                        float ly = fmaxf(ay0, by0[cj]);
                        float rx = fminf(ax1, bx1[cj]);
                        float ry = fminf(ay1, by1[cj]);
                        float iw = fmaxf(rx - lx, 0.0f);
                        float ih = fmaxf(ry - ly, 0.0f);
                        float inter = iw * ih;
                        float iou = inter / (aa + bar[cj] - inter + 1e-7f);
                        if (iou > IOU_T) kf[cj] = 0;
                    }
                }
            }
        }
    }
    __syncthreads();

    // rank kept rows (inclusive scan) and write output
    int kp = kf_s[tid] ? 1 : 0;
    src = sA; dst = sB;
    src[tid] = (unsigned)kp;
    __syncthreads();
    for (int off = 1; off < 1024; off <<= 1) {
        dst[tid] = src[tid] + ((tid >= off) ? src[tid - off] : 0u);
        __syncthreads();
        unsigned* t2 = src; src = dst; dst = t2;
    }
    int rank = (int)src[tid] - kp;

    if (kp && rank < MAX_DET) {
        float* orow = ob + (size_t)rank * 89;
        orow[0] = bx0[tid]; orow[1] = by0[tid];
        orow[2] = bx1[tid]; orow[3] = by1[tid];
        orow[4] = __uint_as_float(t + TBIAS);  // bit-exact top_s
        orow[5] = (float)(int)(mykey & 127u);
        float cl = conf_logits[((size_t)b * NN + n) * 5 + 4];
        float obj_sig = 1.0f / (1.0f + expf(-cl));
        const float4* lrow4 =
            (const float4*)(logits + ((size_t)b * NN + n) * NCLS);
#pragma unroll 4
        for (int q = 0; q < 20; ++q) {
            float4 l4 = lrow4[q];
            orow[6 + 4 * q + 0] = (1.0f / (1.0f + expf(-l4.x))) * obj_sig;
            orow[6 + 4 * q + 1] = (1.0f / (1.0f + expf(-l4.y))) * obj_sig;
            orow[6 + 4 * q + 2] = (1.0f / (1.0f + expf(-l4.z))) * obj_sig;
            orow[6 + 4 * q + 3] = (1.0f / (1.0f + expf(-l4.w))) * obj_sig;
        }
        orow[86] = obj_sig;
        orow[87] = head[(size_t)b * NN + n];
        orow[88] = 1.0f;
    }
}

extern "C" void kernel_launch(void* const* d_in, const int* in_sizes, int n_in,
                              void* d_out, int out_size, void* d_ws,
                              size_t ws_size, hipStream_t stream) {
    const float* pred        = (const float*)d_in[0];
    const float* conf_logits = (const float*)d_in[1];
    const float* logits      = (const float*)d_in[2];
    const float* head        = (const float*)d_in[3];
    float* out = (float*)d_out;

    unsigned long long* keys = (unsigned long long*)d_ws;  // 16*25200*8 B

    dim3 sgrid((NN + RROWS - 1) / RROWS, BATCH);
    score_kernel<<<sgrid, STHREADS, 0, stream>>>(pred, keys);
    fused_kernel<<<BATCH, 1024, 0, stream>>>(keys, pred, conf_logits, logits,
                                             head, out);
}